// Round 14
// baseline (143.306 us; speedup 1.0000x reference)
//
#include <hip/hip_runtime.h>

#define NB 4
#define NS 4096
#define NDIN 1024
#define ND 64

typedef __attribute__((ext_vector_type(4))) float f32x4;
typedef __attribute__((ext_vector_type(8))) short s16x8;
typedef __attribute__((ext_vector_type(4))) short s16x4;

__device__ __forceinline__ unsigned short f2bf(float f) {
  union { float f; unsigned u; } x; x.f = f;
  unsigned r = x.u + 0x7fffu + ((x.u >> 16) & 1u);
  return (unsigned short)(r >> 16);
}

// native packed f32->bf16 (RNE): no builtin on gfx950, inline asm per T12
__device__ __forceinline__ unsigned cvtpk(float lo, float hi) {
  unsigned r;
  asm("v_cvt_pk_bf16_f32 %0, %1, %2" : "=v"(r) : "v"(lo), "v"(hi));
  return r;
}

__device__ __forceinline__ void gload16(const void* g, void* l) {
  __builtin_amdgcn_global_load_lds(
      (const __attribute__((address_space(1))) void*)g,
      (__attribute__((address_space(3))) void*)l, 16, 0, 0);
}

// ---- kernel 0: W -> bf16, transposed to [mat][col][k] for B-fragment reads
__global__ __launch_bounds__(256) void prep_w_kernel(
    const float* __restrict__ Wq, const float* __restrict__ Wk,
    const float* __restrict__ Wv, unsigned short* __restrict__ wt) {
  int idx = blockIdx.x * 256 + threadIdx.x;  // grid sized exactly 3*64*1024
  int m = idx >> 16;
  int r = idx & 65535;
  int c = r >> 10;
  int k = r & 1023;
  const float* W = (m == 0) ? Wq : (m == 1) ? Wk : Wv;
  wt[idx] = f2bf(W[k * ND + c]);
}

// ---- kernel 0b: mask int32 [B][S][S] -> bitmask, 1 bit per element.
// Sequential streams at ~95% DRAM efficiency -- vs ~60% for the scattered
// 256-512B per-row granules when attn streams the raw mask inline (R13).
__global__ __launch_bounds__(256) void mask_pack_kernel(
    const int* __restrict__ mask, unsigned char* __restrict__ bits) {
  const int idx = blockIdx.x * 256 + threadIdx.x;  // 8,388,608 threads, 1 byte each
  const int4* mp = reinterpret_cast<const int4*>(mask) + (size_t)idx * 2;
  const int4 a = mp[0];
  const int4 c = mp[1];
  unsigned v = (unsigned)(a.x != 0) | ((unsigned)(a.y != 0) << 1) |
               ((unsigned)(a.z != 0) << 2) | ((unsigned)(a.w != 0) << 3) |
               ((unsigned)(c.x != 0) << 4) | ((unsigned)(c.y != 0) << 5) |
               ((unsigned)(c.z != 0) << 6) | ((unsigned)(c.w != 0) << 7);
  bits[idx] = (unsigned char)v;
}

// ---- kernel 1: projection X[16384][1024] @ W[1024][64] + b -> bf16
// X staged fp32 via global_load_lds (swizzled 256B rows) AND wt tile staged
// bf16 (swizzled 128B rows). BK=64 double-buffered.
// y==0: q row-major, y==1: k row-major, y==2: v transposed [b][64][4096]
__global__ __launch_bounds__(256, 3) void proj_kernel(
    const float* __restrict__ Xq, const float* __restrict__ Xk, const float* __restrict__ Xv,
    const float* __restrict__ bq, const float* __restrict__ bk, const float* __restrict__ bv,
    const unsigned short* __restrict__ wt_all,
    unsigned short* __restrict__ q_o, unsigned short* __restrict__ k_o,
    unsigned short* __restrict__ vt_o) {
  __shared__ float xsm[2][4096];           // 2 x 16 KB: [64 rows][64 k] fp32, swizzled
  __shared__ unsigned short wsm[2][4096];  // 2 x 8 KB: [64 col][64 k] bf16, swizzled

  const int y = blockIdx.y;
  const float* __restrict__ X = (y == 0) ? Xq : (y == 1) ? Xk : Xv;
  const float* __restrict__ bias = (y == 0) ? bq : (y == 1) ? bk : bv;
  const char* __restrict__ wg = (const char*)(wt_all + y * (ND * NDIN));
  const int row0 = blockIdx.x * 64;
  const int tid = threadIdx.x;
  const int lane = tid & 63;
  const int w = tid >> 6;
  const int ql = lane & 15;
  const int grp = lane >> 4;
  const int swz = (ql & 7) << 4;

  // X staging source offsets: LDS linear o -> pre-swizzled global byte offset
  int osrcX[4];
  #pragma unroll
  for (int j = 0; j < 4; ++j) {
    const int o = w * 4096 + j * 1024 + lane * 16;
    const int row = o >> 8, c = o & 255;
    osrcX[j] = row * 4096 + (c ^ ((row & 7) << 4));
  }
  // W staging source offsets: [64 col][64 k] tile, global row stride 2048 B
  int osrcW[2];
  #pragma unroll
  for (int j = 0; j < 2; ++j) {
    const int o = w * 2048 + j * 1024 + lane * 16;
    const int row = o >> 7, c = o & 127;
    osrcW[j] = row * 2048 + (c ^ ((row & 7) << 4));
  }

  const char* xg = (const char*)(X + (size_t)row0 * NDIN);
  auto stageX = [&](int kk, int buf) {
    const char* src = xg + kk * 256;
    char* dst = (char*)xsm + buf * 16384 + w * 4096;
    #pragma unroll
    for (int j = 0; j < 4; ++j) gload16(src + osrcX[j], dst + j * 1024);
  };
  auto stageW = [&](int kk, int buf) {
    const char* src = wg + kk * 128;
    char* dst = (char*)wsm + buf * 8192 + w * 2048;
    gload16(src + osrcW[0], dst);
    gload16(src + osrcW[1], dst + 1024);
  };

  // W fragment byte columns (within a 128-B row), full-XOR
  const int fw0 = (grp * 16) ^ swz;
  const int fw1 = (grp * 16 + 64) ^ swz;

  f32x4 acc[4] = {};

  stageX(0, 0);
  stageW(0, 0);
  asm volatile("s_waitcnt vmcnt(0)" ::: "memory");
  __syncthreads();

  for (int kk = 0; kk < 16; ++kk) {
    const int cur = kk & 1;
    if (kk < 15) {
      stageX(kk + 1, cur ^ 1);
      stageW(kk + 1, cur ^ 1);
    }
    __builtin_amdgcn_sched_barrier(0);

    const char* xr = (const char*)xsm + cur * 16384 + (16 * w + ql) * 256;
    const char* wr = (const char*)wsm + cur * 8192;
    #pragma unroll
    for (int half = 0; half < 2; ++half) {
      const f32x4 a0 = *reinterpret_cast<const f32x4*>(
          xr + ((half * 128 + grp * 32) ^ swz));
      const f32x4 a1 = *reinterpret_cast<const f32x4*>(
          xr + ((half * 128 + grp * 32 + 16) ^ swz));
      union { s16x8 v; unsigned u[4]; } a;
      a.u[0] = cvtpk(a0[0], a0[1]);
      a.u[1] = cvtpk(a0[2], a0[3]);
      a.u[2] = cvtpk(a1[0], a1[1]);
      a.u[3] = cvtpk(a1[2], a1[3]);
      const int fw = half ? fw1 : fw0;
      #pragma unroll
      for (int nt = 0; nt < 4; ++nt) {
        const s16x8 bfr = *reinterpret_cast<const s16x8*>(wr + (ql + 16 * nt) * 128 + fw);
        acc[nt] = __builtin_amdgcn_mfma_f32_16x16x32_bf16(a.v, bfr, acc[nt], 0, 0, 0);
      }
    }

    asm volatile("s_waitcnt vmcnt(0)" ::: "memory");
    __syncthreads();
  }

  const int b = row0 >> 12;
  const int s0 = row0 & 4095;
  #pragma unroll
  for (int nt = 0; nt < 4; ++nt) {
    const int col = ql + 16 * nt;
    const float bia = bias[col];
    #pragma unroll
    for (int r = 0; r < 4; ++r) {
      const int rr = 16 * w + grp * 4 + r;  // C layout: col=lane&15, row=(lane>>4)*4+r
      const unsigned short h = f2bf(acc[nt][r] + bia);
      if (y == 0) {
        q_o[(size_t)(row0 + rr) * ND + col] = h;
      } else if (y == 1) {
        k_o[(size_t)(row0 + rr) * ND + col] = h;
      } else {
        vt_o[(size_t)b * ND * NS + (size_t)col * NS + (s0 + rr)] = h;
      }
    }
  }
}

// ---- kernel 2: flash attention, LDS-staged K/V (double-buffered, XOR-swizzled),
//      4 waves share kv tile / own 16 q each, kv-split 4 across blocks.
//      Mask from BITMASK: one uint64/lane/tile, ping-pong prefetched a full iter
//      ahead. Per-iter VMEM ledger [stage x4 | SB | mbit x1 | SB]; end-of-iter
//      s_waitcnt vmcnt(1) drains exactly the stage loads, bitmask load stays in
//      flight across the RAW s_barrier (T4). Deferred per-lane softmax (R13).
__global__ __launch_bounds__(256, 4) void attn_kernel(
    const unsigned short* __restrict__ qm, const unsigned short* __restrict__ km,
    const unsigned short* __restrict__ vt, const unsigned char* __restrict__ mbits,
    float* __restrict__ opart, float* __restrict__ ml) {
  __shared__ unsigned short ksm[2][4096];  // [buf][64 kv][64 d], 128B rows, swizzled
  __shared__ unsigned short vsm[2][4096];  // [buf][64 d][64 kv], 128B rows, swizzled
  __shared__ unsigned short psm[4096];     // 4 waves x [16 q][64 kv], swizzled

  const int bid = blockIdx.x;
  const int combo = bid & 15;   // (b,split): bid%8 = XCD -> each XCD sees 2 combos
  const int qblk = bid >> 4;
  const int b = combo >> 2;
  const int split = combo & 3;
  const int q0 = qblk * 64;
  const int kv00 = split * 1024;

  const int tid = threadIdx.x;
  const int lane = tid & 63;
  const int w = tid >> 6;
  const int ql = lane & 15;
  const int grp = lane >> 4;

  // shared swizzle: byte ^= ((row&7)<<4) within 128-B rows; XOR the FULL column
  const int swz = (ql & 7) << 4;
  const int fK0 = ql * 128 + ((grp * 16) ^ swz);        // k-bytes 0..15 of col pair
  const int fK1 = ql * 128 + ((grp * 16 + 64) ^ swz);   // k-bytes 64..79

  // staging source offsets (constant per lane): LDS linear o -> pre-swizzled src
  int oK0, oK1, oV0, oV1;
  {
    const int o0 = w * 2048 + lane * 16;
    const int o1 = o0 + 1024;
    oK0 = o0 ^ (((o0 >> 7) & 7) << 4);
    oK1 = o1 ^ (((o1 >> 7) & 7) << 4);
    const int d0 = o0 >> 7, c0 = o0 & 127;
    const int d1 = o1 >> 7, c1 = o1 & 127;
    oV0 = d0 * 8192 + (c0 ^ ((d0 & 7) << 4));
    oV1 = d1 * 8192 + (c1 ^ ((d1 & 7) << 4));
  }

  const char* kg = (const char*)(km + (size_t)b * NS * ND + (size_t)kv00 * ND);
  const char* vg = (const char*)(vt + (size_t)b * ND * NS + kv00);
  char* const klds = (char*)&ksm[0][0] + w * 2048;
  char* const vlds = (char*)&vsm[0][0] + w * 2048;
  char* const pw = (char*)&psm[0] + w * 2048;

  // Q as B-operand fragments (held for whole kernel)
  const size_t qrow = (size_t)(b * NS + q0 + w * 16 + ql) * ND;
  const s16x8 qf0 = *reinterpret_cast<const s16x8*>(qm + qrow + grp * 8);
  const s16x8 qf1 = *reinterpret_cast<const s16x8*>(qm + qrow + 32 + grp * 8);

  // bitmask row for this lane's q: 512 B/row; this split's window at +split*128;
  // tile t -> uint64 at +t*8 (bit j = kv_local j), 8B-aligned
  const unsigned char* __restrict__ mrow8 =
      mbits + (size_t)(b * NS + q0 + w * 16 + ql) * (NS / 8) + split * 128;

  f32x4 acc[4] = {};
  float m_i = -INFINITY;
  float l_i = 0.f;  // per-lane partial; cross-grp reduced once at epilogue
  const float CSC = 0.18033688011112042f;  // 0.125 * log2(e): exp2 domain
  const float THR = 11.54f;                // ~8/ln2: defer-max threshold

  auto stage = [&](int t, int buf) {
    const char* kt = kg + (size_t)t * 8192;
    const char* vtb = vg + (size_t)t * 128;
    gload16(kt + oK0, klds + buf * 8192);
    gload16(kt + oK1, klds + buf * 8192 + 1024);
    gload16(vtb + oV0, vlds + buf * 8192);
    gload16(vtb + oV1, vlds + buf * 8192 + 1024);
  };

  // one iter: QK^T + bit-mask apply + deferred softmax + P->LDS + PV
  auto body = [&](int t, const char* kread, const char* vread, int buf_next,
                  unsigned long long mbc, unsigned long long& mbn) {
    // ---- stage K/V(t+1) FIRST, sched_barrier, THEN bitmask(t+1): issue order
    // [stage x4, mbit x1] is what makes vmcnt(1) == "stage done".
    if (t < 15) {
      stage(t + 1, buf_next);
      __builtin_amdgcn_sched_barrier(0);
      mbn = *reinterpret_cast<const unsigned long long*>(mrow8 + (t + 1) * 8);
    }
    __builtin_amdgcn_sched_barrier(0);

    // ---- QK^T: A = K (LDS), B = Q (regs) -> S^T[kv][q]
    f32x4 s4[4];
    __builtin_amdgcn_s_setprio(1);
    #pragma unroll
    for (int mt = 0; mt < 4; ++mt) {
      const s16x8 kf0 = *reinterpret_cast<const s16x8*>(kread + mt * 2048 + fK0);
      const s16x8 kf1 = *reinterpret_cast<const s16x8*>(kread + mt * 2048 + fK1);
      f32x4 s = {0.f, 0.f, 0.f, 0.f};
      s = __builtin_amdgcn_mfma_f32_16x16x32_bf16(kf0, qf0, s, 0, 0, 0);
      s = __builtin_amdgcn_mfma_f32_16x16x32_bf16(kf1, qf1, s, 0, 0, 0);
      s4[mt] = s;
    }
    __builtin_amdgcn_s_setprio(0);

    // ---- mask apply from bitmask word (scaled into exp2 domain)
    float sc[16];
    #pragma unroll
    for (int mt = 0; mt < 4; ++mt) {
      const unsigned nib = (unsigned)((mbc >> (16 * mt + 4 * grp)) & 0xFull);
      sc[4 * mt + 0] = (nib & 1u) ? s4[mt][0] * CSC : -1e30f;
      sc[4 * mt + 1] = (nib & 2u) ? s4[mt][1] * CSC : -1e30f;
      sc[4 * mt + 2] = (nib & 4u) ? s4[mt][2] * CSC : -1e30f;
      sc[4 * mt + 3] = (nib & 8u) ? s4[mt][3] * CSC : -1e30f;
    }

    // ---- deferred softmax: no cross-lane ops in the common path
    float t0 = fmaxf(fmaxf(sc[0], sc[1]), fmaxf(sc[2], sc[3]));
    float t1 = fmaxf(fmaxf(sc[4], sc[5]), fmaxf(sc[6], sc[7]));
    float t2 = fmaxf(fmaxf(sc[8], sc[9]), fmaxf(sc[10], sc[11]));
    float t3 = fmaxf(fmaxf(sc[12], sc[13]), fmaxf(sc[14], sc[15]));
    const float tm = fmaxf(fmaxf(t0, t1), fmaxf(t2, t3));
    if (!__all(tm <= m_i + THR)) {
      float tw = fmaxf(tm, __shfl_xor(tm, 16));
      tw = fmaxf(tw, __shfl_xor(tw, 32));
      const float nm = fmaxf(m_i, tw);
      const float alpha = exp2f(m_i - nm);  // first tile: exp2(-inf)=0
      #pragma unroll
      for (int r = 0; r < 4; ++r) {
        const float ar = __shfl(alpha, grp * 4 + r);
        acc[0][r] *= ar;
        acc[1][r] *= ar;
        acc[2][r] *= ar;
        acc[3][r] *= ar;
      }
      l_i *= alpha;
      m_i = nm;
    }
    #pragma unroll
    for (int r = 0; r < 16; ++r) sc[r] = exp2f(sc[r] - m_i);
    float u0 = (sc[0] + sc[1]) + (sc[2] + sc[3]);
    float u1 = (sc[4] + sc[5]) + (sc[6] + sc[7]);
    float u2 = (sc[8] + sc[9]) + (sc[10] + sc[11]);
    float u3 = (sc[12] + sc[13]) + (sc[14] + sc[15]);
    l_i += (u0 + u1) + (u2 + u3);  // per-lane only

    // ---- P -> wave-private LDS (A-layout [q][kv], swizzled) via cvt_pk
    #pragma unroll
    for (int mt = 0; mt < 4; ++mt) {
      uint2 pk;
      pk.x = cvtpk(sc[4 * mt + 0], sc[4 * mt + 1]);
      pk.y = cvtpk(sc[4 * mt + 2], sc[4 * mt + 3]);
      *reinterpret_cast<uint2*>(pw + ql * 128 + ((mt * 32 + grp * 8) ^ swz)) = pk;
    }

    // ---- PV: A = P (LDS), B = V^T (LDS) -> O[q][d]; V frag cols == fK0/fK1
    #pragma unroll
    for (int ks = 0; ks < 2; ++ks) {
      const s16x8 pa = *reinterpret_cast<const s16x8*>(
          pw + ql * 128 + ((ks * 64 + grp * 16) ^ swz));
      const int fV = ks ? fK1 : fK0;
      __builtin_amdgcn_s_setprio(1);
      #pragma unroll
      for (int nt = 0; nt < 4; ++nt) {
        const s16x8 vb = *reinterpret_cast<const s16x8*>(vread + nt * 2048 + fV);
        acc[nt] = __builtin_amdgcn_mfma_f32_16x16x32_bf16(pa, vb, acc[nt], 0, 0, 0);
      }
      __builtin_amdgcn_s_setprio(0);
    }

    // counted vmcnt(1): drains this wave's 4 stage loads (oldest in FIFO, order
    // pinned above); the bitmask load stays in flight across the RAW s_barrier.
    if (t < 15) {
      asm volatile("s_waitcnt vmcnt(1)" ::: "memory");
      __builtin_amdgcn_s_barrier();
    }
  };

  const char* const kbuf0 = (const char*)&ksm[0][0];
  const char* const kbuf1 = (const char*)&ksm[0][0] + 8192;
  const char* const vbuf0 = (const char*)&vsm[0][0];
  const char* const vbuf1 = (const char*)&vsm[0][0] + 8192;

  unsigned long long mbA, mbB;
  stage(0, 0);
  mbA = *reinterpret_cast<const unsigned long long*>(mrow8);
  asm volatile("s_waitcnt vmcnt(0)" ::: "memory");
  __syncthreads();

  for (int tt = 0; tt < 16; tt += 2) {
    body(tt, kbuf0, vbuf0, 1, mbA, mbB);
    body(tt + 1, kbuf1, vbuf1, 0, mbB, mbA);
  }

  // ---- epilogue: cross-grp l reduction (deferred from the loop)
  float lq = l_i + __shfl_xor(l_i, 16);
  lq += __shfl_xor(lq, 32);

  const int qg = b * NS + q0 + w * 16;
  float* obase = opart + ((size_t)split * (NB * NS) + qg) * 64;
  #pragma unroll
  for (int nt = 0; nt < 4; ++nt) {
    #pragma unroll
    for (int r = 0; r < 4; ++r) {
      obase[(size_t)(grp * 4 + r) * 64 + ql + 16 * nt] = acc[nt][r];
    }
  }
  if (grp == 0) {
    float* mlp = ml + ((size_t)split * (NB * NS) + qg + ql) * 2;
    mlp[0] = m_i;
    mlp[1] = lq;
  }
}

// ---- kernel 3: LSE-combine the 4 kv-split partials (exp2 domain)
__global__ __launch_bounds__(256) void combine_kernel(
    const float* __restrict__ opart, const float* __restrict__ ml,
    float* __restrict__ out) {
  const int idx = blockIdx.x * 256 + threadIdx.x;  // 262144 threads
  const int q = idx >> 4;
  const int dc = (idx & 15) * 4;
  const float2 a0 = *reinterpret_cast<const float2*>(ml + (size_t)q * 2);
  const float2 a1 = *reinterpret_cast<const float2*>(ml + (size_t)(16384 + q) * 2);
  const float2 a2 = *reinterpret_cast<const float2*>(ml + (size_t)(32768 + q) * 2);
  const float2 a3 = *reinterpret_cast<const float2*>(ml + (size_t)(49152 + q) * 2);
  const float M = fmaxf(fmaxf(a0.x, a1.x), fmaxf(a2.x, a3.x));
  const float w0 = exp2f(a0.x - M), w1 = exp2f(a1.x - M);
  const float w2 = exp2f(a2.x - M), w3 = exp2f(a3.x - M);
  const float inv = 1.f / (a0.y * w0 + a1.y * w1 + a2.y * w2 + a3.y * w3);
  f32x4 o = (*reinterpret_cast<const f32x4*>(opart + (size_t)q * 64 + dc)) * w0;
  o += (*reinterpret_cast<const f32x4*>(opart + ((size_t)16384 + q) * 64 + dc)) * w1;
  o += (*reinterpret_cast<const f32x4*>(opart + ((size_t)32768 + q) * 64 + dc)) * w2;
  o += (*reinterpret_cast<const f32x4*>(opart + ((size_t)49152 + q) * 64 + dc)) * w3;
  o *= inv;
  *reinterpret_cast<f32x4*>(out + (size_t)q * 64 + dc) = o;
}

extern "C" void kernel_launch(void* const* d_in, const int* in_sizes, int n_in,
                              void* d_out, int out_size, void* d_ws, size_t ws_size,
                              hipStream_t stream) {
  const float* query = (const float*)d_in[0];
  const float* key   = (const float*)d_in[1];
  const float* value = (const float*)d_in[2];
  const int*   mask  = (const int*)d_in[3];
  const float* Wq = (const float*)d_in[4];
  const float* bq = (const float*)d_in[5];
  const float* Wk = (const float*)d_in[6];
  const float* bk = (const float*)d_in[7];
  const float* Wv = (const float*)d_in[8];
  const float* bv = (const float*)d_in[9];
  float* out = (float*)d_out;

  char* ws = (char*)d_ws;
  unsigned short* wt    = (unsigned short*)(ws);               // 384 KB
  unsigned short* qb    = (unsigned short*)(ws + 393216);      // 2 MB
  unsigned short* kb    = (unsigned short*)(ws + 2490368);     // 2 MB
  unsigned short* vtb   = (unsigned short*)(ws + 4587520);     // 2 MB
  unsigned char*  mbits = (unsigned char*)(ws + 6684672);      // 8 MB
  float*          opart = (float*)(ws + 15073280);             // 16 MB
  float*          mlb   = (float*)(ws + 31850496);             // 512 KB

  prep_w_kernel<<<dim3(768), dim3(256), 0, stream>>>(Wq, Wk, Wv, wt);
  mask_pack_kernel<<<dim3(32768), dim3(256), 0, stream>>>(mask, mbits);
  proj_kernel<<<dim3(256, 3), dim3(256), 0, stream>>>(query, key, value,
                                                      bq, bk, bv, wt, qb, kb, vtb);
  attn_kernel<<<dim3(1024), dim3(256), 0, stream>>>(qb, kb, vtb, mbits, opart, mlb);
  combine_kernel<<<dim3(1024), dim3(256), 0, stream>>>(opart, mlb, out);
}

// Round 15
// 131.633 us; speedup vs baseline: 1.0887x; 1.0887x over previous
//
#include <hip/hip_runtime.h>

#define NB 4
#define NS 4096
#define NDIN 1024
#define ND 64

typedef __attribute__((ext_vector_type(4))) float f32x4;
typedef __attribute__((ext_vector_type(8))) short s16x8;
typedef __attribute__((ext_vector_type(4))) short s16x4;

__device__ __forceinline__ unsigned short f2bf(float f) {
  union { float f; unsigned u; } x; x.f = f;
  unsigned r = x.u + 0x7fffu + ((x.u >> 16) & 1u);
  return (unsigned short)(r >> 16);
}

// native packed f32->bf16 (RNE): no builtin on gfx950, inline asm per T12
__device__ __forceinline__ unsigned cvtpk(float lo, float hi) {
  unsigned r;
  asm("v_cvt_pk_bf16_f32 %0, %1, %2" : "=v"(r) : "v"(lo), "v"(hi));
  return r;
}

__device__ __forceinline__ void gload16(const void* g, void* l) {
  __builtin_amdgcn_global_load_lds(
      (const __attribute__((address_space(1))) void*)g,
      (__attribute__((address_space(3))) void*)l, 16, 0, 0);
}

// ---- kernel 0: W -> bf16, transposed to [mat][col][k] for B-fragment reads
__global__ __launch_bounds__(256) void prep_w_kernel(
    const float* __restrict__ Wq, const float* __restrict__ Wk,
    const float* __restrict__ Wv, unsigned short* __restrict__ wt) {
  int idx = blockIdx.x * 256 + threadIdx.x;  // grid sized exactly 3*64*1024
  int m = idx >> 16;
  int r = idx & 65535;
  int c = r >> 10;
  int k = r & 1023;
  const float* W = (m == 0) ? Wq : (m == 1) ? Wk : Wv;
  wt[idx] = f2bf(W[k * ND + c]);
}

// ---- kernel 1: projection X[16384][1024] @ W[1024][64] + b -> bf16
// X staged fp32 via global_load_lds (swizzled 256B rows) AND wt tile staged
// bf16 (swizzled 128B rows). BK=64 double-buffered.
// y==0: q row-major, y==1: k row-major, y==2: v transposed [b][64][4096]
__global__ __launch_bounds__(256, 3) void proj_kernel(
    const float* __restrict__ Xq, const float* __restrict__ Xk, const float* __restrict__ Xv,
    const float* __restrict__ bq, const float* __restrict__ bk, const float* __restrict__ bv,
    const unsigned short* __restrict__ wt_all,
    unsigned short* __restrict__ q_o, unsigned short* __restrict__ k_o,
    unsigned short* __restrict__ vt_o) {
  __shared__ float xsm[2][4096];           // 2 x 16 KB: [64 rows][64 k] fp32, swizzled
  __shared__ unsigned short wsm[2][4096];  // 2 x 8 KB: [64 col][64 k] bf16, swizzled

  const int y = blockIdx.y;
  const float* __restrict__ X = (y == 0) ? Xq : (y == 1) ? Xk : Xv;
  const float* __restrict__ bias = (y == 0) ? bq : (y == 1) ? bk : bv;
  const char* __restrict__ wg = (const char*)(wt_all + y * (ND * NDIN));
  const int row0 = blockIdx.x * 64;
  const int tid = threadIdx.x;
  const int lane = tid & 63;
  const int w = tid >> 6;
  const int ql = lane & 15;
  const int grp = lane >> 4;
  const int swz = (ql & 7) << 4;

  // X staging source offsets: LDS linear o -> pre-swizzled global byte offset
  int osrcX[4];
  #pragma unroll
  for (int j = 0; j < 4; ++j) {
    const int o = w * 4096 + j * 1024 + lane * 16;
    const int row = o >> 8, c = o & 255;
    osrcX[j] = row * 4096 + (c ^ ((row & 7) << 4));
  }
  // W staging source offsets: [64 col][64 k] tile, global row stride 2048 B
  int osrcW[2];
  #pragma unroll
  for (int j = 0; j < 2; ++j) {
    const int o = w * 2048 + j * 1024 + lane * 16;
    const int row = o >> 7, c = o & 127;
    osrcW[j] = row * 2048 + (c ^ ((row & 7) << 4));
  }

  const char* xg = (const char*)(X + (size_t)row0 * NDIN);
  auto stageX = [&](int kk, int buf) {
    const char* src = xg + kk * 256;
    char* dst = (char*)xsm + buf * 16384 + w * 4096;
    #pragma unroll
    for (int j = 0; j < 4; ++j) gload16(src + osrcX[j], dst + j * 1024);
  };
  auto stageW = [&](int kk, int buf) {
    const char* src = wg + kk * 128;
    char* dst = (char*)wsm + buf * 8192 + w * 2048;
    gload16(src + osrcW[0], dst);
    gload16(src + osrcW[1], dst + 1024);
  };

  // W fragment byte columns (within a 128-B row), full-XOR
  const int fw0 = (grp * 16) ^ swz;
  const int fw1 = (grp * 16 + 64) ^ swz;

  f32x4 acc[4] = {};

  stageX(0, 0);
  stageW(0, 0);
  asm volatile("s_waitcnt vmcnt(0)" ::: "memory");
  __syncthreads();

  for (int kk = 0; kk < 16; ++kk) {
    const int cur = kk & 1;
    if (kk < 15) {
      stageX(kk + 1, cur ^ 1);
      stageW(kk + 1, cur ^ 1);
    }
    __builtin_amdgcn_sched_barrier(0);

    const char* xr = (const char*)xsm + cur * 16384 + (16 * w + ql) * 256;
    const char* wr = (const char*)wsm + cur * 8192;
    #pragma unroll
    for (int half = 0; half < 2; ++half) {
      const f32x4 a0 = *reinterpret_cast<const f32x4*>(
          xr + ((half * 128 + grp * 32) ^ swz));
      const f32x4 a1 = *reinterpret_cast<const f32x4*>(
          xr + ((half * 128 + grp * 32 + 16) ^ swz));
      union { s16x8 v; unsigned u[4]; } a;
      a.u[0] = cvtpk(a0[0], a0[1]);
      a.u[1] = cvtpk(a0[2], a0[3]);
      a.u[2] = cvtpk(a1[0], a1[1]);
      a.u[3] = cvtpk(a1[2], a1[3]);
      const int fw = half ? fw1 : fw0;
      #pragma unroll
      for (int nt = 0; nt < 4; ++nt) {
        const s16x8 bfr = *reinterpret_cast<const s16x8*>(wr + (ql + 16 * nt) * 128 + fw);
        acc[nt] = __builtin_amdgcn_mfma_f32_16x16x32_bf16(a.v, bfr, acc[nt], 0, 0, 0);
      }
    }

    asm volatile("s_waitcnt vmcnt(0)" ::: "memory");
    __syncthreads();
  }

  const int b = row0 >> 12;
  const int s0 = row0 & 4095;
  #pragma unroll
  for (int nt = 0; nt < 4; ++nt) {
    const int col = ql + 16 * nt;
    const float bia = bias[col];
    #pragma unroll
    for (int r = 0; r < 4; ++r) {
      const int rr = 16 * w + grp * 4 + r;  // C layout: col=lane&15, row=(lane>>4)*4+r
      const unsigned short h = f2bf(acc[nt][r] + bia);
      if (y == 0) {
        q_o[(size_t)(row0 + rr) * ND + col] = h;
      } else if (y == 1) {
        k_o[(size_t)(row0 + rr) * ND + col] = h;
      } else {
        vt_o[(size_t)b * ND * NS + (size_t)col * NS + (s0 + rr)] = h;
      }
    }
  }
}

// ---- kernel 2: flash attention, LDS-staged K/V (double-buffered, XOR-swizzled),
//      4 waves share kv tile / own 16 q each. kv-split 2: 512 blocks, exactly
//      2/CU at (256,2) -- zero tail, 32k mask streams (half of R13), 32 iters.
//      Mask in 1KB-per-row bursts: windows of 4 iters; at window top issue all
//      16 int4 for the NEXT window into a ping-pong bank (MA/MB, static index).
//      Consume-lag = 4 iters (~10us >> HBM latency) -> plain __syncthreads()
//      everywhere; sched_barrier(0) only pins the burst issue point.
__global__ __launch_bounds__(256, 2) void attn_kernel(
    const unsigned short* __restrict__ qm, const unsigned short* __restrict__ km,
    const unsigned short* __restrict__ vt, const int* __restrict__ mask,
    float* __restrict__ opart, float* __restrict__ ml) {
  __shared__ unsigned short ksm[2][4096];  // [buf][64 kv][64 d], 128B rows, swizzled
  __shared__ unsigned short vsm[2][4096];  // [buf][64 d][64 kv], 128B rows, swizzled
  __shared__ unsigned short psm[4096];     // 4 waves x [16 q][64 kv], swizzled

  const int bid = blockIdx.x;
  const int combo = bid & 7;    // (b,split): bid%8 = XCD -> each XCD owns 1 combo
  const int qblk = bid >> 3;    // 0..63
  const int b = combo >> 1;
  const int split = combo & 1;
  const int q0 = qblk * 64;
  const int kv00 = split * 2048;

  const int tid = threadIdx.x;
  const int lane = tid & 63;
  const int w = tid >> 6;
  const int ql = lane & 15;
  const int grp = lane >> 4;

  // shared swizzle: byte ^= ((row&7)<<4) within 128-B rows; XOR the FULL column
  const int swz = (ql & 7) << 4;
  const int fK0 = ql * 128 + ((grp * 16) ^ swz);        // k-bytes 0..15 of col pair
  const int fK1 = ql * 128 + ((grp * 16 + 64) ^ swz);   // k-bytes 64..79

  // staging source offsets (constant per lane): LDS linear o -> pre-swizzled src
  int oK0, oK1, oV0, oV1;
  {
    const int o0 = w * 2048 + lane * 16;
    const int o1 = o0 + 1024;
    oK0 = o0 ^ (((o0 >> 7) & 7) << 4);
    oK1 = o1 ^ (((o1 >> 7) & 7) << 4);
    const int d0 = o0 >> 7, c0 = o0 & 127;
    const int d1 = o1 >> 7, c1 = o1 & 127;
    oV0 = d0 * 8192 + (c0 ^ ((d0 & 7) << 4));
    oV1 = d1 * 8192 + (c1 ^ ((d1 & 7) << 4));
  }

  const char* kg = (const char*)(km + (size_t)b * NS * ND + (size_t)kv00 * ND);
  const char* vg = (const char*)(vt + (size_t)b * ND * NS + kv00);
  char* const klds = (char*)&ksm[0][0] + w * 2048;
  char* const vlds = (char*)&vsm[0][0] + w * 2048;
  char* const pw = (char*)&psm[0] + w * 2048;

  // Q as B-operand fragments (held for whole kernel)
  const size_t qrow = (size_t)(b * NS + q0 + w * 16 + ql) * ND;
  const s16x8 qf0 = *reinterpret_cast<const s16x8*>(qm + qrow + grp * 8);
  const s16x8 qf1 = *reinterpret_cast<const s16x8*>(qm + qrow + 32 + grp * 8);

  // raw mask row for this lane's q: 8KB window, walked in 1KB bursts
  const int* __restrict__ mrow =
      mask + (size_t)(b * NS + q0 + w * 16 + ql) * NS + kv00;

  f32x4 acc[4] = {};
  float m_i = -INFINITY;
  float l_i = 0.f;  // per-lane partial; cross-grp reduced once at epilogue
  const float CSC = 0.18033688011112042f;  // 0.125 * log2(e): exp2 domain
  const float THR = 11.54f;                // ~8/ln2: defer-max threshold

  auto stage = [&](int t, int buf) {
    const char* kt = kg + (size_t)t * 8192;
    const char* vtb = vg + (size_t)t * 128;
    gload16(kt + oK0, klds + buf * 8192);
    gload16(kt + oK1, klds + buf * 8192 + 1024);
    gload16(vtb + oV0, vlds + buf * 8192);
    gload16(vtb + oV1, vlds + buf * 8192 + 1024);
  };

  // 16 back-to-back int4 loads: tiles tau..tau+3 (1KB contiguous per row)
  auto mburst = [&](int4 (&dst)[4][4], int tau) {
    #pragma unroll
    for (int i = 0; i < 4; ++i) {
      const int* mp = mrow + (tau + i) * 64 + grp * 4;
      dst[i][0] = *reinterpret_cast<const int4*>(mp);
      dst[i][1] = *reinterpret_cast<const int4*>(mp + 16);
      dst[i][2] = *reinterpret_cast<const int4*>(mp + 32);
      dst[i][3] = *reinterpret_cast<const int4*>(mp + 48);
    }
  };

  // one iter: QK^T + mask apply + deferred softmax + P->LDS + PV
  auto body = [&](const char* kread, const char* vread, const int4 (&m)[4]) {
    f32x4 s4[4];
    __builtin_amdgcn_s_setprio(1);
    #pragma unroll
    for (int mt = 0; mt < 4; ++mt) {
      const s16x8 kf0 = *reinterpret_cast<const s16x8*>(kread + mt * 2048 + fK0);
      const s16x8 kf1 = *reinterpret_cast<const s16x8*>(kread + mt * 2048 + fK1);
      f32x4 s = {0.f, 0.f, 0.f, 0.f};
      s = __builtin_amdgcn_mfma_f32_16x16x32_bf16(kf0, qf0, s, 0, 0, 0);
      s = __builtin_amdgcn_mfma_f32_16x16x32_bf16(kf1, qf1, s, 0, 0, 0);
      s4[mt] = s;
    }
    __builtin_amdgcn_s_setprio(0);

    float sc[16];
    #pragma unroll
    for (int mt = 0; mt < 4; ++mt) {
      sc[4 * mt + 0] = (m[mt].x != 0) ? s4[mt][0] * CSC : -1e30f;
      sc[4 * mt + 1] = (m[mt].y != 0) ? s4[mt][1] * CSC : -1e30f;
      sc[4 * mt + 2] = (m[mt].z != 0) ? s4[mt][2] * CSC : -1e30f;
      sc[4 * mt + 3] = (m[mt].w != 0) ? s4[mt][3] * CSC : -1e30f;
    }

    // deferred softmax: no cross-lane ops in the common path
    float t0 = fmaxf(fmaxf(sc[0], sc[1]), fmaxf(sc[2], sc[3]));
    float t1 = fmaxf(fmaxf(sc[4], sc[5]), fmaxf(sc[6], sc[7]));
    float t2 = fmaxf(fmaxf(sc[8], sc[9]), fmaxf(sc[10], sc[11]));
    float t3 = fmaxf(fmaxf(sc[12], sc[13]), fmaxf(sc[14], sc[15]));
    const float tm = fmaxf(fmaxf(t0, t1), fmaxf(t2, t3));
    if (!__all(tm <= m_i + THR)) {
      float tw = fmaxf(tm, __shfl_xor(tm, 16));
      tw = fmaxf(tw, __shfl_xor(tw, 32));
      const float nm = fmaxf(m_i, tw);
      const float alpha = exp2f(m_i - nm);  // first tile: exp2(-inf)=0
      #pragma unroll
      for (int r = 0; r < 4; ++r) {
        const float ar = __shfl(alpha, grp * 4 + r);
        acc[0][r] *= ar;
        acc[1][r] *= ar;
        acc[2][r] *= ar;
        acc[3][r] *= ar;
      }
      l_i *= alpha;
      m_i = nm;
    }
    #pragma unroll
    for (int r = 0; r < 16; ++r) sc[r] = exp2f(sc[r] - m_i);
    float u0 = (sc[0] + sc[1]) + (sc[2] + sc[3]);
    float u1 = (sc[4] + sc[5]) + (sc[6] + sc[7]);
    float u2 = (sc[8] + sc[9]) + (sc[10] + sc[11]);
    float u3 = (sc[12] + sc[13]) + (sc[14] + sc[15]);
    l_i += (u0 + u1) + (u2 + u3);  // per-lane only

    #pragma unroll
    for (int mt = 0; mt < 4; ++mt) {
      uint2 pk;
      pk.x = cvtpk(sc[4 * mt + 0], sc[4 * mt + 1]);
      pk.y = cvtpk(sc[4 * mt + 2], sc[4 * mt + 3]);
      *reinterpret_cast<uint2*>(pw + ql * 128 + ((mt * 32 + grp * 8) ^ swz)) = pk;
    }
    #pragma unroll
    for (int ks = 0; ks < 2; ++ks) {
      const s16x8 pa = *reinterpret_cast<const s16x8*>(
          pw + ql * 128 + ((ks * 64 + grp * 16) ^ swz));
      const int fV = ks ? fK1 : fK0;
      __builtin_amdgcn_s_setprio(1);
      #pragma unroll
      for (int nt = 0; nt < 4; ++nt) {
        const s16x8 vb = *reinterpret_cast<const s16x8*>(vread + nt * 2048 + fV);
        acc[nt] = __builtin_amdgcn_mfma_f32_16x16x32_bf16(pa, vb, acc[nt], 0, 0, 0);
      }
      __builtin_amdgcn_s_setprio(0);
    }
  };

  const char* const kbuf0 = (const char*)&ksm[0][0];
  const char* const kbuf1 = (const char*)&ksm[0][0] + 8192;
  const char* const vbuf0 = (const char*)&vsm[0][0];
  const char* const vbuf1 = (const char*)&vsm[0][0] + 8192;

  int4 MA[4][4], MB[4][4];  // ping-pong mask banks, statically indexed

  // prologue: stage tile0; burst window0 (tiles 0..3) -> MA
  stage(0, 0);
  mburst(MA, 0);
  asm volatile("s_waitcnt vmcnt(0)" ::: "memory");
  __syncthreads();

  // window of 4 iters; tiles 4W..4W+3 consumed from cur, next window -> nxt
  auto window = [&](int W, const int4 (&cur)[4][4], int4 (&nxt)[4][4]) {
    const int T = 4 * W;
    // p0 (tile T, buf0)
    stage(T + 1, 1);
    if (W < 7) mburst(nxt, T + 4);
    __builtin_amdgcn_sched_barrier(0);
    body(kbuf0, vbuf0, cur[0]);
    __syncthreads();
    // p1 (tile T+1, buf1)
    stage(T + 2, 0);
    __builtin_amdgcn_sched_barrier(0);
    body(kbuf1, vbuf1, cur[1]);
    __syncthreads();
    // p2 (tile T+2, buf0)
    stage(T + 3, 1);
    __builtin_amdgcn_sched_barrier(0);
    body(kbuf0, vbuf0, cur[2]);
    __syncthreads();
    // p3 (tile T+3, buf1)
    if (T + 4 < 32) {
      stage(T + 4, 0);
      __builtin_amdgcn_sched_barrier(0);
      body(kbuf1, vbuf1, cur[3]);
      __syncthreads();
    } else {
      body(kbuf1, vbuf1, cur[3]);
    }
  };

  for (int WW = 0; WW < 8; WW += 2) {
    window(WW, MA, MB);
    window(WW + 1, MB, MA);
  }

  // ---- epilogue: cross-grp l reduction (deferred from the loop)
  float lq = l_i + __shfl_xor(l_i, 16);
  lq += __shfl_xor(lq, 32);

  const int qg = b * NS + q0 + w * 16;
  float* obase = opart + ((size_t)split * (NB * NS) + qg) * 64;
  #pragma unroll
  for (int nt = 0; nt < 4; ++nt) {
    #pragma unroll
    for (int r = 0; r < 4; ++r) {
      obase[(size_t)(grp * 4 + r) * 64 + ql + 16 * nt] = acc[nt][r];
    }
  }
  if (grp == 0) {
    float* mlp = ml + ((size_t)split * (NB * NS) + qg + ql) * 2;
    mlp[0] = m_i;
    mlp[1] = lq;
  }
}

// ---- kernel 3: LSE-combine the 2 kv-split partials (exp2 domain)
__global__ __launch_bounds__(256) void combine_kernel(
    const float* __restrict__ opart, const float* __restrict__ ml,
    float* __restrict__ out) {
  const int idx = blockIdx.x * 256 + threadIdx.x;  // 262144 threads
  const int q = idx >> 4;
  const int dc = (idx & 15) * 4;
  const float2 a0 = *reinterpret_cast<const float2*>(ml + (size_t)q * 2);
  const float2 a1 = *reinterpret_cast<const float2*>(ml + (size_t)(16384 + q) * 2);
  const float M = fmaxf(a0.x, a1.x);
  const float w0 = exp2f(a0.x - M), w1 = exp2f(a1.x - M);
  const float inv = 1.f / (a0.y * w0 + a1.y * w1);
  f32x4 o = (*reinterpret_cast<const f32x4*>(opart + (size_t)q * 64 + dc)) * w0;
  o += (*reinterpret_cast<const f32x4*>(opart + ((size_t)16384 + q) * 64 + dc)) * w1;
  o *= inv;
  *reinterpret_cast<f32x4*>(out + (size_t)q * 64 + dc) = o;
}

extern "C" void kernel_launch(void* const* d_in, const int* in_sizes, int n_in,
                              void* d_out, int out_size, void* d_ws, size_t ws_size,
                              hipStream_t stream) {
  const float* query = (const float*)d_in[0];
  const float* key   = (const float*)d_in[1];
  const float* value = (const float*)d_in[2];
  const int*   mask  = (const int*)d_in[3];
  const float* Wq = (const float*)d_in[4];
  const float* bq = (const float*)d_in[5];
  const float* Wk = (const float*)d_in[6];
  const float* bk = (const float*)d_in[7];
  const float* Wv = (const float*)d_in[8];
  const float* bv = (const float*)d_in[9];
  float* out = (float*)d_out;

  char* ws = (char*)d_ws;
  unsigned short* wt    = (unsigned short*)(ws);               // 384 KB
  unsigned short* qb    = (unsigned short*)(ws + 393216);      // 2 MB
  unsigned short* kb    = (unsigned short*)(ws + 2490368);     // 2 MB
  unsigned short* vtb   = (unsigned short*)(ws + 4587520);     // 2 MB
  float*          opart = (float*)(ws + 6684672);              // 8.4 MB (2 splits)
  float*          mlb   = (float*)(ws + 23461888);             // 256 KB

  prep_w_kernel<<<dim3(768), dim3(256), 0, stream>>>(Wq, Wk, Wv, wt);
  proj_kernel<<<dim3(256, 3), dim3(256), 0, stream>>>(query, key, value,
                                                      bq, bk, bv, wt, qb, kb, vtb);
  attn_kernel<<<dim3(512), dim3(256), 0, stream>>>(qb, kb, vtb, mask, opart, mlb);
  combine_kernel<<<dim3(1024), dim3(256), 0, stream>>>(opart, mlb, out);
}

// Round 16
// 124.962 us; speedup vs baseline: 1.1468x; 1.0534x over previous
//
#include <hip/hip_runtime.h>

#define NB 4
#define NS 4096
#define NDIN 1024
#define ND 64

typedef __attribute__((ext_vector_type(4))) float f32x4;
typedef __attribute__((ext_vector_type(8))) short s16x8;
typedef __attribute__((ext_vector_type(4))) short s16x4;

__device__ __forceinline__ unsigned short f2bf(float f) {
  union { float f; unsigned u; } x; x.f = f;
  unsigned r = x.u + 0x7fffu + ((x.u >> 16) & 1u);
  return (unsigned short)(r >> 16);
}

__device__ __forceinline__ float bf2f(unsigned short h) {
  union { unsigned u; float f; } x; x.u = ((unsigned)h) << 16;
  return x.f;
}

// native packed f32->bf16 (RNE): no builtin on gfx950, inline asm per T12
__device__ __forceinline__ unsigned cvtpk(float lo, float hi) {
  unsigned r;
  asm("v_cvt_pk_bf16_f32 %0, %1, %2" : "=v"(r) : "v"(lo), "v"(hi));
  return r;
}

__device__ __forceinline__ void gload16(const void* g, void* l) {
  __builtin_amdgcn_global_load_lds(
      (const __attribute__((address_space(1))) void*)g,
      (__attribute__((address_space(3))) void*)l, 16, 0, 0);
}

// ---- kernel 0: W -> bf16, transposed to [mat][col][k] for B-fragment reads
__global__ __launch_bounds__(256) void prep_w_kernel(
    const float* __restrict__ Wq, const float* __restrict__ Wk,
    const float* __restrict__ Wv, unsigned short* __restrict__ wt) {
  int idx = blockIdx.x * 256 + threadIdx.x;  // grid sized exactly 3*64*1024
  int m = idx >> 16;
  int r = idx & 65535;
  int c = r >> 10;
  int k = r & 1023;
  const float* W = (m == 0) ? Wq : (m == 1) ? Wk : Wv;
  wt[idx] = f2bf(W[k * ND + c]);
}

// ---- kernel 1: projection X[16384][1024] @ W[1024][64] + b -> bf16
// X staged fp32 via global_load_lds (swizzled 256B rows) AND wt tile staged
// bf16 (swizzled 128B rows). BK=64 double-buffered.
// y==0: q row-major, y==1: k row-major, y==2: v transposed [b][64][4096]
__global__ __launch_bounds__(256, 3) void proj_kernel(
    const float* __restrict__ Xq, const float* __restrict__ Xk, const float* __restrict__ Xv,
    const float* __restrict__ bq, const float* __restrict__ bk, const float* __restrict__ bv,
    const unsigned short* __restrict__ wt_all,
    unsigned short* __restrict__ q_o, unsigned short* __restrict__ k_o,
    unsigned short* __restrict__ vt_o) {
  __shared__ float xsm[2][4096];           // 2 x 16 KB: [64 rows][64 k] fp32, swizzled
  __shared__ unsigned short wsm[2][4096];  // 2 x 8 KB: [64 col][64 k] bf16, swizzled

  const int y = blockIdx.y;
  const float* __restrict__ X = (y == 0) ? Xq : (y == 1) ? Xk : Xv;
  const float* __restrict__ bias = (y == 0) ? bq : (y == 1) ? bk : bv;
  const char* __restrict__ wg = (const char*)(wt_all + y * (ND * NDIN));
  const int row0 = blockIdx.x * 64;
  const int tid = threadIdx.x;
  const int lane = tid & 63;
  const int w = tid >> 6;
  const int ql = lane & 15;
  const int grp = lane >> 4;
  const int swz = (ql & 7) << 4;

  // X staging source offsets: LDS linear o -> pre-swizzled global byte offset
  int osrcX[4];
  #pragma unroll
  for (int j = 0; j < 4; ++j) {
    const int o = w * 4096 + j * 1024 + lane * 16;
    const int row = o >> 8, c = o & 255;
    osrcX[j] = row * 4096 + (c ^ ((row & 7) << 4));
  }
  // W staging source offsets: [64 col][64 k] tile, global row stride 2048 B
  int osrcW[2];
  #pragma unroll
  for (int j = 0; j < 2; ++j) {
    const int o = w * 2048 + j * 1024 + lane * 16;
    const int row = o >> 7, c = o & 127;
    osrcW[j] = row * 2048 + (c ^ ((row & 7) << 4));
  }

  const char* xg = (const char*)(X + (size_t)row0 * NDIN);
  auto stageX = [&](int kk, int buf) {
    const char* src = xg + kk * 256;
    char* dst = (char*)xsm + buf * 16384 + w * 4096;
    #pragma unroll
    for (int j = 0; j < 4; ++j) gload16(src + osrcX[j], dst + j * 1024);
  };
  auto stageW = [&](int kk, int buf) {
    const char* src = wg + kk * 128;
    char* dst = (char*)wsm + buf * 8192 + w * 2048;
    gload16(src + osrcW[0], dst);
    gload16(src + osrcW[1], dst + 1024);
  };

  // W fragment byte columns (within a 128-B row), full-XOR
  const int fw0 = (grp * 16) ^ swz;
  const int fw1 = (grp * 16 + 64) ^ swz;

  f32x4 acc[4] = {};

  stageX(0, 0);
  stageW(0, 0);
  asm volatile("s_waitcnt vmcnt(0)" ::: "memory");
  __syncthreads();

  for (int kk = 0; kk < 16; ++kk) {
    const int cur = kk & 1;
    if (kk < 15) {
      stageX(kk + 1, cur ^ 1);
      stageW(kk + 1, cur ^ 1);
    }
    __builtin_amdgcn_sched_barrier(0);

    const char* xr = (const char*)xsm + cur * 16384 + (16 * w + ql) * 256;
    const char* wr = (const char*)wsm + cur * 8192;
    #pragma unroll
    for (int half = 0; half < 2; ++half) {
      const f32x4 a0 = *reinterpret_cast<const f32x4*>(
          xr + ((half * 128 + grp * 32) ^ swz));
      const f32x4 a1 = *reinterpret_cast<const f32x4*>(
          xr + ((half * 128 + grp * 32 + 16) ^ swz));
      union { s16x8 v; unsigned u[4]; } a;
      a.u[0] = cvtpk(a0[0], a0[1]);
      a.u[1] = cvtpk(a0[2], a0[3]);
      a.u[2] = cvtpk(a1[0], a1[1]);
      a.u[3] = cvtpk(a1[2], a1[3]);
      const int fw = half ? fw1 : fw0;
      #pragma unroll
      for (int nt = 0; nt < 4; ++nt) {
        const s16x8 bfr = *reinterpret_cast<const s16x8*>(wr + (ql + 16 * nt) * 128 + fw);
        acc[nt] = __builtin_amdgcn_mfma_f32_16x16x32_bf16(a.v, bfr, acc[nt], 0, 0, 0);
      }
    }

    asm volatile("s_waitcnt vmcnt(0)" ::: "memory");
    __syncthreads();
  }

  const int b = row0 >> 12;
  const int s0 = row0 & 4095;
  #pragma unroll
  for (int nt = 0; nt < 4; ++nt) {
    const int col = ql + 16 * nt;
    const float bia = bias[col];
    #pragma unroll
    for (int r = 0; r < 4; ++r) {
      const int rr = 16 * w + grp * 4 + r;  // C layout: col=lane&15, row=(lane>>4)*4+r
      const unsigned short h = f2bf(acc[nt][r] + bia);
      if (y == 0) {
        q_o[(size_t)(row0 + rr) * ND + col] = h;
      } else if (y == 1) {
        k_o[(size_t)(row0 + rr) * ND + col] = h;
      } else {
        vt_o[(size_t)b * ND * NS + (size_t)col * NS + (s0 + rr)] = h;
      }
    }
  }
}

// ---- kernel 2: flash attention (R13 structure, verified 125.8us config):
//      LDS-staged K/V (double-buffered, XOR-swizzled), 4 waves x 16 q,
//      kv-split 4 across blocks (1024 blocks = 4/CU, zero tail).
//      Mask read in 512B-per-row bursts: tiles {t+1,t+2} batched (8 x int4)
//      every EVEN iter into mcA/mcB ping-pong. Even-end vmcnt(8) keeps the
//      batch flying; odd-end vmcnt(0). Deferred per-lane softmax.
//      Split partials written as BF16 (halves opart round trip vs R13).
__global__ __launch_bounds__(256, 4) void attn_kernel(
    const unsigned short* __restrict__ qm, const unsigned short* __restrict__ km,
    const unsigned short* __restrict__ vt, const int* __restrict__ mask,
    unsigned short* __restrict__ opart, float* __restrict__ ml) {
  __shared__ unsigned short ksm[2][4096];  // [buf][64 kv][64 d], 128B rows, swizzled
  __shared__ unsigned short vsm[2][4096];  // [buf][64 d][64 kv], 128B rows, swizzled
  __shared__ unsigned short psm[4096];     // 4 waves x [16 q][64 kv], swizzled

  const int bid = blockIdx.x;
  const int combo = bid & 15;   // (b,split): bid%8 = XCD -> each XCD sees 2 combos
  const int qblk = bid >> 4;
  const int b = combo >> 2;
  const int split = combo & 3;
  const int q0 = qblk * 64;
  const int kv00 = split * 1024;

  const int tid = threadIdx.x;
  const int lane = tid & 63;
  const int w = tid >> 6;
  const int ql = lane & 15;
  const int grp = lane >> 4;

  // shared swizzle: byte ^= ((row&7)<<4) within 128-B rows; XOR the FULL column
  const int swz = (ql & 7) << 4;
  const int fK0 = ql * 128 + ((grp * 16) ^ swz);        // k-bytes 0..15 of col pair
  const int fK1 = ql * 128 + ((grp * 16 + 64) ^ swz);   // k-bytes 64..79

  // staging source offsets (constant per lane): LDS linear o -> pre-swizzled src
  int oK0, oK1, oV0, oV1;
  {
    const int o0 = w * 2048 + lane * 16;
    const int o1 = o0 + 1024;
    oK0 = o0 ^ (((o0 >> 7) & 7) << 4);
    oK1 = o1 ^ (((o1 >> 7) & 7) << 4);
    const int d0 = o0 >> 7, c0 = o0 & 127;
    const int d1 = o1 >> 7, c1 = o1 & 127;
    oV0 = d0 * 8192 + (c0 ^ ((d0 & 7) << 4));
    oV1 = d1 * 8192 + (c1 ^ ((d1 & 7) << 4));
  }

  const char* kg = (const char*)(km + (size_t)b * NS * ND + (size_t)kv00 * ND);
  const char* vg = (const char*)(vt + (size_t)b * ND * NS + kv00);
  char* const klds = (char*)&ksm[0][0] + w * 2048;
  char* const vlds = (char*)&vsm[0][0] + w * 2048;
  char* const pw = (char*)&psm[0] + w * 2048;

  // Q as B-operand fragments (held for whole kernel)
  const size_t qrow = (size_t)(b * NS + q0 + w * 16 + ql) * ND;
  const s16x8 qf0 = *reinterpret_cast<const s16x8*>(qm + qrow + grp * 8);
  const s16x8 qf1 = *reinterpret_cast<const s16x8*>(qm + qrow + 32 + grp * 8);

  // raw mask row for this lane's q; consumed 64 kv (4 x int4) per tile
  const int* __restrict__ mrow =
      mask + (size_t)(b * NS + q0 + w * 16 + ql) * NS + kv00;

  f32x4 acc[4] = {};
  float m_i = -INFINITY;
  float l_i = 0.f;  // per-lane partial; cross-grp reduced once at epilogue
  const float CSC = 0.18033688011112042f;  // 0.125 * log2(e): exp2 domain
  const float THR = 11.54f;                // ~8/ln2: defer-max threshold

  auto stage = [&](int t, int buf) {
    const char* kt = kg + (size_t)t * 8192;
    const char* vtb = vg + (size_t)t * 128;
    gload16(kt + oK0, klds + buf * 8192);
    gload16(kt + oK1, klds + buf * 8192 + 1024);
    gload16(vtb + oV0, vlds + buf * 8192);
    gload16(vtb + oV1, vlds + buf * 8192 + 1024);
  };

  int4 mcA[4], mcB[4];  // two mask tile sets (ping-pong), statically indexed

  auto mload = [&](int4 (&m)[4], int tau) {
    const int* mn = mrow + tau * 64;
    m[0] = *reinterpret_cast<const int4*>(mn + grp * 4);
    m[1] = *reinterpret_cast<const int4*>(mn + 16 + grp * 4);
    m[2] = *reinterpret_cast<const int4*>(mn + 32 + grp * 4);
    m[3] = *reinterpret_cast<const int4*>(mn + 48 + grp * 4);
  };

  // QK^T + mask apply -> sc (exp2 domain)
  auto qk_apply = [&](const char* kread, const int4 (&m)[4], float (&sc)[16]) {
    f32x4 s4[4];
    __builtin_amdgcn_s_setprio(1);
    #pragma unroll
    for (int mt = 0; mt < 4; ++mt) {
      const s16x8 kf0 = *reinterpret_cast<const s16x8*>(kread + mt * 2048 + fK0);
      const s16x8 kf1 = *reinterpret_cast<const s16x8*>(kread + mt * 2048 + fK1);
      f32x4 s = {0.f, 0.f, 0.f, 0.f};
      s = __builtin_amdgcn_mfma_f32_16x16x32_bf16(kf0, qf0, s, 0, 0, 0);
      s = __builtin_amdgcn_mfma_f32_16x16x32_bf16(kf1, qf1, s, 0, 0, 0);
      s4[mt] = s;
    }
    __builtin_amdgcn_s_setprio(0);
    #pragma unroll
    for (int mt = 0; mt < 4; ++mt) {
      sc[4 * mt + 0] = (m[mt].x != 0) ? s4[mt][0] * CSC : -1e30f;
      sc[4 * mt + 1] = (m[mt].y != 0) ? s4[mt][1] * CSC : -1e30f;
      sc[4 * mt + 2] = (m[mt].z != 0) ? s4[mt][2] * CSC : -1e30f;
      sc[4 * mt + 3] = (m[mt].w != 0) ? s4[mt][3] * CSC : -1e30f;
    }
  };

  // softmax (per-lane deferred) + P->LDS + PV
  auto finish = [&](const char* vread, float (&sc)[16]) {
    float t0 = fmaxf(fmaxf(sc[0], sc[1]), fmaxf(sc[2], sc[3]));
    float t1 = fmaxf(fmaxf(sc[4], sc[5]), fmaxf(sc[6], sc[7]));
    float t2 = fmaxf(fmaxf(sc[8], sc[9]), fmaxf(sc[10], sc[11]));
    float t3 = fmaxf(fmaxf(sc[12], sc[13]), fmaxf(sc[14], sc[15]));
    const float tm = fmaxf(fmaxf(t0, t1), fmaxf(t2, t3));
    // common path: no cross-lane ops; full reduce only when max grows
    if (!__all(tm <= m_i + THR)) {
      float tw = fmaxf(tm, __shfl_xor(tm, 16));
      tw = fmaxf(tw, __shfl_xor(tw, 32));
      const float nm = fmaxf(m_i, tw);
      const float alpha = exp2f(m_i - nm);  // first tile: exp2(-inf)=0
      #pragma unroll
      for (int r = 0; r < 4; ++r) {
        const float ar = __shfl(alpha, grp * 4 + r);
        acc[0][r] *= ar;
        acc[1][r] *= ar;
        acc[2][r] *= ar;
        acc[3][r] *= ar;
      }
      l_i *= alpha;
      m_i = nm;
    }
    #pragma unroll
    for (int r = 0; r < 16; ++r) sc[r] = exp2f(sc[r] - m_i);
    float u0 = (sc[0] + sc[1]) + (sc[2] + sc[3]);
    float u1 = (sc[4] + sc[5]) + (sc[6] + sc[7]);
    float u2 = (sc[8] + sc[9]) + (sc[10] + sc[11]);
    float u3 = (sc[12] + sc[13]) + (sc[14] + sc[15]);
    l_i += (u0 + u1) + (u2 + u3);  // per-lane only

    #pragma unroll
    for (int mt = 0; mt < 4; ++mt) {
      uint2 pk;
      pk.x = cvtpk(sc[4 * mt + 0], sc[4 * mt + 1]);
      pk.y = cvtpk(sc[4 * mt + 2], sc[4 * mt + 3]);
      *reinterpret_cast<uint2*>(pw + ql * 128 + ((mt * 32 + grp * 8) ^ swz)) = pk;
    }
    #pragma unroll
    for (int ks = 0; ks < 2; ++ks) {
      const s16x8 pa = *reinterpret_cast<const s16x8*>(
          pw + ql * 128 + ((ks * 64 + grp * 16) ^ swz));
      const int fV = ks ? fK1 : fK0;
      __builtin_amdgcn_s_setprio(1);
      #pragma unroll
      for (int nt = 0; nt < 4; ++nt) {
        const s16x8 vb = *reinterpret_cast<const s16x8*>(vread + nt * 2048 + fV);
        acc[nt] = __builtin_amdgcn_mfma_f32_16x16x32_bf16(pa, vb, acc[nt], 0, 0, 0);
      }
      __builtin_amdgcn_s_setprio(0);
    }
  };

  const char* const kbuf0 = (const char*)&ksm[0][0];
  const char* const kbuf1 = (const char*)&ksm[0][0] + 8192;
  const char* const vbuf0 = (const char*)&vsm[0][0];
  const char* const vbuf1 = (const char*)&vsm[0][0] + 8192;

  // prologue: stage tile0, load mask tile0 -> mcB
  stage(0, 0);
  mload(mcB, 0);
  asm volatile("s_waitcnt vmcnt(0)" ::: "memory");
  __syncthreads();

  for (int tt = 0; tt < 14; tt += 2) {
    // ---- EVEN t=tt (buf0): stage(t+1); consume mcB; batch-load {t+1,t+2}
    float sc[16];
    stage(tt + 1, 1);
    __builtin_amdgcn_sched_barrier(0);
    qk_apply(kbuf0, mcB, sc);
    mload(mcA, tt + 1);          // 8 int4 = 512B-per-row burst window
    mload(mcB, tt + 2);
    __builtin_amdgcn_sched_barrier(0);
    finish(vbuf0, sc);
    // drain stage4 (oldest), keep batch8 in flight across the raw barrier
    asm volatile("s_waitcnt vmcnt(8)" ::: "memory");
    __builtin_amdgcn_s_barrier();

    // ---- ODD t=tt+1 (buf1): stage(t+1); consume mcA; no mask loads
    float sd[16];
    stage(tt + 2, 0);
    __builtin_amdgcn_sched_barrier(0);
    qk_apply(kbuf1, mcA, sd);
    __builtin_amdgcn_sched_barrier(0);
    finish(vbuf1, sd);
    // stage4 is youngest -> full drain; batch remnants are ~1.5 iters old
    asm volatile("s_waitcnt vmcnt(0)" ::: "memory");
    __builtin_amdgcn_s_barrier();
  }

  {  // ---- t=14 (buf0): stage(15); consume mcB; load tile15 -> mcA
    float sc[16];
    stage(15, 1);
    __builtin_amdgcn_sched_barrier(0);
    qk_apply(kbuf0, mcB, sc);
    mload(mcA, 15);
    __builtin_amdgcn_sched_barrier(0);
    finish(vbuf0, sc);
    asm volatile("s_waitcnt vmcnt(4)" ::: "memory");
    __builtin_amdgcn_s_barrier();
  }
  {  // ---- t=15 (buf1): consume mcA; no stage, no end sync
    float sc[16];
    qk_apply(kbuf1, mcA, sc);
    finish(vbuf1, sc);
  }

  // ---- epilogue: cross-grp l reduction (deferred from the loop)
  float lq = l_i + __shfl_xor(l_i, 16);
  lq += __shfl_xor(lq, 32);

  const int qg = b * NS + q0 + w * 16;
  unsigned short* obase = opart + ((size_t)split * (NB * NS) + qg) * 64;
  #pragma unroll
  for (int nt = 0; nt < 4; ++nt) {
    #pragma unroll
    for (int r = 0; r < 4; ++r) {
      obase[(size_t)(grp * 4 + r) * 64 + ql + 16 * nt] = f2bf(acc[nt][r]);
    }
  }
  if (grp == 0) {
    float* mlp = ml + ((size_t)split * (NB * NS) + qg + ql) * 2;
    mlp[0] = m_i;
    mlp[1] = lq;
  }
}

// ---- kernel 3: LSE-combine the 4 kv-split partials (exp2 domain, bf16 opart)
__global__ __launch_bounds__(256) void combine_kernel(
    const unsigned short* __restrict__ opart, const float* __restrict__ ml,
    float* __restrict__ out) {
  const int idx = blockIdx.x * 256 + threadIdx.x;  // 262144 threads
  const int q = idx >> 4;
  const int dc = (idx & 15) * 4;
  const float2 a0 = *reinterpret_cast<const float2*>(ml + (size_t)q * 2);
  const float2 a1 = *reinterpret_cast<const float2*>(ml + (size_t)(16384 + q) * 2);
  const float2 a2 = *reinterpret_cast<const float2*>(ml + (size_t)(32768 + q) * 2);
  const float2 a3 = *reinterpret_cast<const float2*>(ml + (size_t)(49152 + q) * 2);
  const float M = fmaxf(fmaxf(a0.x, a1.x), fmaxf(a2.x, a3.x));
  const float w0 = exp2f(a0.x - M), w1 = exp2f(a1.x - M);
  const float w2 = exp2f(a2.x - M), w3 = exp2f(a3.x - M);
  const float inv = 1.f / (a0.y * w0 + a1.y * w1 + a2.y * w2 + a3.y * w3);
  const ushort4 o0 = *reinterpret_cast<const ushort4*>(opart + (size_t)q * 64 + dc);
  const ushort4 o1 = *reinterpret_cast<const ushort4*>(opart + ((size_t)16384 + q) * 64 + dc);
  const ushort4 o2 = *reinterpret_cast<const ushort4*>(opart + ((size_t)32768 + q) * 64 + dc);
  const ushort4 o3 = *reinterpret_cast<const ushort4*>(opart + ((size_t)49152 + q) * 64 + dc);
  f32x4 o;
  o[0] = (bf2f(o0.x) * w0 + bf2f(o1.x) * w1 + bf2f(o2.x) * w2 + bf2f(o3.x) * w3) * inv;
  o[1] = (bf2f(o0.y) * w0 + bf2f(o1.y) * w1 + bf2f(o2.y) * w2 + bf2f(o3.y) * w3) * inv;
  o[2] = (bf2f(o0.z) * w0 + bf2f(o1.z) * w1 + bf2f(o2.z) * w2 + bf2f(o3.z) * w3) * inv;
  o[3] = (bf2f(o0.w) * w0 + bf2f(o1.w) * w1 + bf2f(o2.w) * w2 + bf2f(o3.w) * w3) * inv;
  *reinterpret_cast<f32x4*>(out + (size_t)q * 64 + dc) = o;
}

extern "C" void kernel_launch(void* const* d_in, const int* in_sizes, int n_in,
                              void* d_out, int out_size, void* d_ws, size_t ws_size,
                              hipStream_t stream) {
  const float* query = (const float*)d_in[0];
  const float* key   = (const float*)d_in[1];
  const float* value = (const float*)d_in[2];
  const int*   mask  = (const int*)d_in[3];
  const float* Wq = (const float*)d_in[4];
  const float* bq = (const float*)d_in[5];
  const float* Wk = (const float*)d_in[6];
  const float* bk = (const float*)d_in[7];
  const float* Wv = (const float*)d_in[8];
  const float* bv = (const float*)d_in[9];
  float* out = (float*)d_out;

  char* ws = (char*)d_ws;
  unsigned short* wt    = (unsigned short*)(ws);               // 384 KB
  unsigned short* qb    = (unsigned short*)(ws + 393216);      // 2 MB
  unsigned short* kb    = (unsigned short*)(ws + 2490368);     // 2 MB
  unsigned short* vtb   = (unsigned short*)(ws + 4587520);     // 2 MB
  unsigned short* opart = (unsigned short*)(ws + 6684672);     // 8 MB (bf16)
  float*          mlb   = (float*)(ws + 15073280);             // 512 KB

  prep_w_kernel<<<dim3(768), dim3(256), 0, stream>>>(Wq, Wk, Wv, wt);
  proj_kernel<<<dim3(256, 3), dim3(256), 0, stream>>>(query, key, value,
                                                      bq, bk, bv, wt, qb, kb, vtb);
  attn_kernel<<<dim3(1024), dim3(256), 0, stream>>>(qb, kb, vtb, mask, opart, mlb);
  combine_kernel<<<dim3(1024), dim3(256), 0, stream>>>(opart, mlb, out);
}